// Round 2
// baseline (1179.292 us; speedup 1.0000x reference)
//
#include <hip/hip_runtime.h>
#include <hip/hip_bf16.h>
#include <stdint.h>

using short8 = __attribute__((ext_vector_type(8))) short;
using f32x4  = __attribute__((ext_vector_type(4))) float;

#define DD 1152
#define ROW 6912   // QKV row stride (elements)

static __device__ __forceinline__ float bf2f(uint32_t h){
  union { uint32_t u; float f; } v; v.u = (h & 0xffffu) << 16; return v.f;
}
static __device__ __forceinline__ ushort f2bf(float f){
  union { float f; uint32_t u; } v; v.f = f;
  uint32_t r = (v.u + 0x7fffu + ((v.u >> 16) & 1u)) >> 16;
  return (ushort)r;
}
static __device__ __forceinline__ uint32_t pack2(float a, float b){
  return (uint32_t)f2bf(a) | ((uint32_t)f2bf(b) << 16);
}

static __device__ __forceinline__ void gload16(const void* g, void* l){
  __builtin_amdgcn_global_load_lds(
      (const __attribute__((address_space(1))) void*)g,
      (__attribute__((address_space(3))) void*)l, 16, 0, 0);
}

// ---------------- generic NT GEMM: C[m][n] = sum_k A[m][k] * B[n][k] ----------------
// 128x128 tile, BK=64, 4 waves (each 64x64 = 4x4 fragments of 16x16x32 bf16 MFMA)
#define BM 128
#define BN 128
#define BK 64

// EPI: 0 = bf16 store (ldc), 1 = fp32 store (alpha applied), 2 = split@1152 + bias -> out0/out1
template<int EPI>
__global__ __launch_bounds__(256)
void gemm_bt(const ushort* __restrict__ A, int lda,
             const ushort* __restrict__ Bm, int ldb,
             void* __restrict__ Cout, int ldc,
             int K, float alpha, int row0,
             float* __restrict__ out0, float* __restrict__ out1,
             const float* __restrict__ bias0, const float* __restrict__ bias1)
{
  __shared__ __align__(16) ushort lA[BM * BK];
  __shared__ __align__(16) ushort lB[BN * BK];
  const int tid  = threadIdx.x;
  const int wave = tid >> 6, lane = tid & 63;
  const int wr = wave >> 1, wc = wave & 1;
  const int m0 = blockIdx.y * BM, n0 = blockIdx.x * BN;

  const int sr = lane >> 3;        // row within 8-row segment
  const int sc = (lane & 7) * 8;   // col (elements)

  f32x4 acc[4][4];
#pragma unroll
  for (int m = 0; m < 4; m++)
#pragma unroll
    for (int n = 0; n < 4; n++) acc[m][n] = f32x4{0.f, 0.f, 0.f, 0.f};

  for (int kt = 0; kt < K; kt += BK) {
#pragma unroll
    for (int i = 0; i < 4; i++) {
      int seg = wave * 4 + i;
      gload16(A + (size_t)(m0 + seg * 8 + sr) * lda + kt + sc, (void*)(lA + seg * 512));
    }
#pragma unroll
    for (int i = 0; i < 4; i++) {
      int seg = wave * 4 + i;
      gload16(Bm + (size_t)(n0 + seg * 8 + sr) * ldb + kt + sc, (void*)(lB + seg * 512));
    }
    __syncthreads();
#pragma unroll
    for (int kk = 0; kk < BK; kk += 32) {
      short8 af[4], bfr[4];
#pragma unroll
      for (int m = 0; m < 4; m++)
        af[m] = *(const short8*)(lA + (wr * 64 + m * 16 + (lane & 15)) * BK + kk + (lane >> 4) * 8);
#pragma unroll
      for (int n = 0; n < 4; n++)
        bfr[n] = *(const short8*)(lB + (wc * 64 + n * 16 + (lane & 15)) * BK + kk + (lane >> 4) * 8);
#pragma unroll
      for (int m = 0; m < 4; m++)
#pragma unroll
        for (int n = 0; n < 4; n++)
          acc[m][n] = __builtin_amdgcn_mfma_f32_16x16x32_bf16(af[m], bfr[n], acc[m][n], 0, 0, 0);
    }
    __syncthreads();
  }

#pragma unroll
  for (int m = 0; m < 4; m++) {
#pragma unroll
    for (int v = 0; v < 4; v++) {
      int row = m0 + wr * 64 + m * 16 + (lane >> 4) * 4 + v;
#pragma unroll
      for (int n = 0; n < 4; n++) {
        int col = n0 + wc * 64 + n * 16 + (lane & 15);
        float val = acc[m][n][v] * alpha;
        if (EPI == 0) {
          ((ushort*)Cout)[(size_t)row * ldc + col] = f2bf(val);
        } else if (EPI == 1) {
          ((float*)Cout)[(size_t)row * ldc + col] = val;
        } else {
          int orow = row0 + row;
          if (col < DD) out0[(size_t)orow * DD + col] = val + bias0[col];
          else          out1[(size_t)orow * DD + (col - DD)] = val + bias1[col - DD];
        }
      }
    }
  }
}

// ---------------- fp32 -> bf16 conversion ----------------
__global__ __launch_bounds__(256)
void cvt_f32_bf16(const float* __restrict__ src, ushort* __restrict__ dst, int n4)
{
  int stride = gridDim.x * blockDim.x;
  for (int i = blockIdx.x * blockDim.x + threadIdx.x; i < n4; i += stride) {
    float4 v = ((const float4*)src)[i];
    uint2 o;
    o.x = pack2(v.x, v.y);
    o.y = pack2(v.z, v.w);
    ((uint2*)dst)[i] = o;
  }
}

// ---------------- in-place RMS norm on Q/K segments of QKV rows ----------------
// row layout: [q_text q_pix k_text k_pix v_text v_pix] each 1152
// wave w handles segment w (0..3); butterfly reduce => no LDS needed
__global__ __launch_bounds__(256)
void rms_inplace(ushort* __restrict__ qkv,
                 const float* __restrict__ sq_text, const float* __restrict__ sq_pix,
                 const float* __restrict__ sk_text, const float* __restrict__ sk_pix)
{
  const int row = blockIdx.x;
  const int tid = threadIdx.x, wave = tid >> 6, lane = tid & 63;
  ushort* seg = qkv + (size_t)row * ROW + wave * 1152;
  const float* scale = (wave == 0) ? sq_text : (wave == 1) ? sq_pix
                     : (wave == 2) ? sk_text : sk_pix;
  float ss = 0.f;
  for (int g = lane; g < 144; g += 64) {
    uint4 p = *(const uint4*)(seg + g * 8);
    float f0 = bf2f(p.x), f1 = bf2f(p.x >> 16), f2 = bf2f(p.y), f3 = bf2f(p.y >> 16);
    float f4 = bf2f(p.z), f5 = bf2f(p.z >> 16), f6 = bf2f(p.w), f7 = bf2f(p.w >> 16);
    ss += f0*f0 + f1*f1 + f2*f2 + f3*f3 + f4*f4 + f5*f5 + f6*f6 + f7*f7;
  }
#pragma unroll
  for (int off = 32; off; off >>= 1) ss += __shfl_xor(ss, off);
  float rms = sqrtf(ss) * 0.0294627825f;  // 1/sqrt(1152)
  float inv = 1.0f / (rms + 1e-8f);
  for (int g = lane; g < 144; g += 64) {
    int d0 = g * 8;
    uint4 p = *(const uint4*)(seg + d0);
    float f[8];
    f[0]=bf2f(p.x); f[1]=bf2f(p.x>>16); f[2]=bf2f(p.y); f[3]=bf2f(p.y>>16);
    f[4]=bf2f(p.z); f[5]=bf2f(p.z>>16); f[6]=bf2f(p.w); f[7]=bf2f(p.w>>16);
    uint4 o;
    o.x = pack2(f[0]*scale[d0+0]*inv, f[1]*scale[d0+1]*inv);
    o.y = pack2(f[2]*scale[d0+2]*inv, f[3]*scale[d0+3]*inv);
    o.z = pack2(f[4]*scale[d0+4]*inv, f[5]*scale[d0+5]*inv);
    o.w = pack2(f[6]*scale[d0+6]*inv, f[7]*scale[d0+7]*inv);
    *(uint4*)(seg + d0) = o;
  }
}

// ---------------- V transpose: Vt[b][d][n] = V[b][n][d] (V = qkv cols 4608..6911) ----------------
__global__ __launch_bounds__(256)
void transpose_v(const ushort* __restrict__ qkv, ushort* __restrict__ Vt)
{
  __shared__ ushort t[64][72];
  const int nb = blockIdx.x, db = blockIdx.y, b = blockIdx.z;
  const int tid = threadIdx.x;
  const int d0 = db * 64;
  const int srccol = 4608 + d0;
  const int rr = tid >> 3, cc = (tid & 7) * 8;
#pragma unroll
  for (int it = 0; it < 2; it++) {
    int r = rr + it * 32;
    uint4 p = *(const uint4*)(qkv + (size_t)(b * 4096 + nb * 64 + r) * ROW + srccol + cc);
    *(uint4*)&t[r][cc] = p;
  }
  __syncthreads();
#pragma unroll
  for (int it = 0; it < 2; it++) {
    int d = rr + it * 32;
    uint4 o;
    o.x = (uint32_t)t[cc+0][d] | ((uint32_t)t[cc+1][d] << 16);
    o.y = (uint32_t)t[cc+2][d] | ((uint32_t)t[cc+3][d] << 16);
    o.z = (uint32_t)t[cc+4][d] | ((uint32_t)t[cc+5][d] << 16);
    o.w = (uint32_t)t[cc+6][d] | ((uint32_t)t[cc+7][d] << 16);
    *(uint4*)(Vt + ((size_t)b * 2304 + d0 + d) * 4096 + nb * 64 + cc) = o;
  }
}

// ---------------- row softmax: S fp32 (4096 wide) -> P bf16 in place (ld 8192 ushorts) ----------------
__global__ __launch_bounds__(256)
void softmax_row(float* __restrict__ S)
{
  const int row = blockIdx.x;
  float* sr = S + (size_t)row * 4096;
  const int tid = threadIdx.x, wave = tid >> 6, lane = tid & 63;
  __shared__ float red[8];
  float4 x[4];
#pragma unroll
  for (int j = 0; j < 4; j++) x[j] = *(const float4*)(sr + j * 1024 + tid * 4);
  float mx = -3.4e38f;
#pragma unroll
  for (int j = 0; j < 4; j++)
    mx = fmaxf(mx, fmaxf(fmaxf(x[j].x, x[j].y), fmaxf(x[j].z, x[j].w)));
#pragma unroll
  for (int off = 32; off; off >>= 1) mx = fmaxf(mx, __shfl_xor(mx, off));
  if (lane == 0) red[wave] = mx;
  __syncthreads();
  mx = fmaxf(fmaxf(red[0], red[1]), fmaxf(red[2], red[3]));
  float s = 0.f;
#pragma unroll
  for (int j = 0; j < 4; j++) {
    x[j].x = expf(x[j].x - mx); x[j].y = expf(x[j].y - mx);
    x[j].z = expf(x[j].z - mx); x[j].w = expf(x[j].w - mx);
    s += x[j].x + x[j].y + x[j].z + x[j].w;
  }
#pragma unroll
  for (int off = 32; off; off >>= 1) s += __shfl_xor(s, off);
  if (lane == 0) red[4 + wave] = s;
  __syncthreads();
  s = red[4] + red[5] + red[6] + red[7];
  float inv = 1.0f / s;
  ushort* p = (ushort*)sr;
#pragma unroll
  for (int j = 0; j < 4; j++) {
    uint2 o;
    o.x = pack2(x[j].x * inv, x[j].y * inv);
    o.y = pack2(x[j].z * inv, x[j].w * inv);
    *(uint2*)(p + j * 1024 + tid * 4) = o;
  }
}

// ---------------- host launch ----------------
extern "C" void kernel_launch(void* const* d_in, const int* in_sizes, int n_in,
                              void* d_out, int out_size, void* d_ws, size_t ws_size,
                              hipStream_t stream)
{
  const float* x          = (const float*)d_in[0];
  const float* Wqkv_pix   = (const float*)d_in[2];
  const float* Wqkv_text  = (const float*)d_in[3];
  const float* sq_text    = (const float*)d_in[4];
  const float* sk_text    = (const float*)d_in[5];
  const float* sq_pix     = (const float*)d_in[6];
  const float* sk_pix     = (const float*)d_in[7];
  const float* Wproj_pix  = (const float*)d_in[8];
  const float* bproj_pix  = (const float*)d_in[9];
  const float* Wproj_text = (const float*)d_in[10];
  const float* bproj_text = (const float*)d_in[11];

  // workspace layout (bytes):
  //  QKV  [0,          113,246,208)   8192x6912 bf16 (q_text q_pix k_text k_pix v_text v_pix)
  //  Vt   [113,246,208,150,994,944)   2x 2304x4096 bf16   (xb aliased here pre-transpose)
  //  S    [150,994,944,184,549,376)   2048x4096 fp32 chunk (Wb aliased here pre-attention)
  //  Zc   [184,549,376,193,986,560)   2048x2304 bf16 chunk
  //  Wpb  [193,986,560,204,603,392)   2304x2304 bf16 packed proj weights
  if (ws_size < 204603392ULL) return;  // diagnostic: clean fail => ws too small
  char* ws = (char*)d_ws;
  ushort* QKV = (ushort*)(ws);
  ushort* Vt  = (ushort*)(ws + 113246208);
  float*  S   = (float*) (ws + 150994944);
  ushort* Zc  = (ushort*)(ws + 184549376);
  ushort* Wpb = (ushort*)(ws + 193986560);
  ushort* xb  = (ushort*)(ws + 113246208);   // alias (dead before Vt written)
  ushort* Wb  = (ushort*)(ws + 150994944);   // alias (dead before S written)

  // conversions; Wb packed in 1152-row blocks: [q_text q_pix k_text k_pix v_text v_pix]
  cvt_f32_bf16<<<2048, 256, 0, stream>>>(x, xb, 9437184 / 4);
  for (int t = 0; t < 3; t++) {
    cvt_f32_bf16<<<512, 256, 0, stream>>>(Wqkv_text + (size_t)t * 1327104,
                                          Wb + (size_t)(2 * t) * 1327104, 1327104 / 4);
    cvt_f32_bf16<<<512, 256, 0, stream>>>(Wqkv_pix + (size_t)t * 1327104,
                                          Wb + (size_t)(2 * t + 1) * 1327104, 1327104 / 4);
  }
  cvt_f32_bf16<<<512, 256, 0, stream>>>(Wproj_pix, Wpb, 2654208 / 4);
  cvt_f32_bf16<<<512, 256, 0, stream>>>(Wproj_text, Wpb + 2654208, 2654208 / 4);

  // G1: QKV = xb @ Wb^T   (8192 x 6912, K=1152)
  {
    dim3 g(6912 / BN, 8192 / BM);
    gemm_bt<0><<<g, 256, 0, stream>>>(xb, 1152, Wb, 1152, QKV, ROW, 1152, 1.0f, 0,
                                      nullptr, nullptr, nullptr, nullptr);
  }
  rms_inplace<<<8192, 256, 0, stream>>>(QKV, sq_text, sq_pix, sk_text, sk_pix);
  {
    dim3 g(64, 36, 2);
    transpose_v<<<g, 256, 0, stream>>>(QKV, Vt);
  }

  const float scale = 1.0f / 48.0f;  // (2*1152)^-0.5
  for (int b = 0; b < 2; b++) {
    const ushort* Kp = QKV + (size_t)b * 4096 * ROW + 2304;
    const ushort* Vb = Vt + (size_t)b * 2304 * 4096;
    for (int h = 0; h < 2; h++) {
      const ushort* Qc = QKV + (size_t)(b * 4096 + h * 2048) * ROW;
      // S = scale * Qc @ K^T   (2048 x 4096, K=2304)
      {
        dim3 g(4096 / BN, 2048 / BM);
        gemm_bt<1><<<g, 256, 0, stream>>>(Qc, ROW, Kp, ROW, S, 4096, 2304, scale, 0,
                                          nullptr, nullptr, nullptr, nullptr);
      }
      softmax_row<<<2048, 256, 0, stream>>>(S);
      // Zc = P @ V  (P bf16 in S rows, lda=8192 ushorts; B = Vt so NT form)
      {
        dim3 g(2304 / BN, 2048 / BM);
        gemm_bt<0><<<g, 256, 0, stream>>>((const ushort*)S, 8192, Vb, 4096, Zc, 2304,
                                          4096, 1.0f, 0, nullptr, nullptr, nullptr, nullptr);
      }
      // out rows [row0, row0+2048) = Zc @ Wp^T, split at col 1152 + bias
      {
        dim3 g(2304 / BN, 2048 / BM);
        float* out0 = (float*)d_out;
        float* out1 = out0 + 9437184;
        gemm_bt<2><<<g, 256, 0, stream>>>(Zc, 2304, Wpb, 2304, nullptr, 0, 2304, 1.0f,
                                          b * 4096 + h * 2048,
                                          out0, out1, bproj_pix, bproj_text);
      }
    }
  }
}

// Round 3
// 761.510 us; speedup vs baseline: 1.5486x; 1.5486x over previous
//
#include <hip/hip_runtime.h>
#include <hip/hip_bf16.h>
#include <stdint.h>

using short8 = __attribute__((ext_vector_type(8))) short;
using f32x4  = __attribute__((ext_vector_type(4))) float;

#define DD 1152
#define ROW 6912   // QKV row stride (elements)

static __device__ __forceinline__ float bf2f(uint32_t h){
  union { uint32_t u; float f; } v; v.u = (h & 0xffffu) << 16; return v.f;
}
static __device__ __forceinline__ ushort f2bf(float f){
  union { float f; uint32_t u; } v; v.f = f;
  uint32_t r = (v.u + 0x7fffu + ((v.u >> 16) & 1u)) >> 16;
  return (ushort)r;
}
static __device__ __forceinline__ uint32_t pack2(float a, float b){
  return (uint32_t)f2bf(a) | ((uint32_t)f2bf(b) << 16);
}

static __device__ __forceinline__ void gload16(const void* g, void* l){
  __builtin_amdgcn_global_load_lds(
      (const __attribute__((address_space(1))) void*)g,
      (__attribute__((address_space(3))) void*)l, 16, 0, 0);
}

// ================= 256x256 NT GEMM, BK=32, 8 waves, 4-deep LDS pipeline ==============
// C[m][n] = alpha * sum_k A[m][k]*B[n][k]
// - waves 2(M)x4(N), per-wave 128x64 output = 8x4 frags of 16x16x32 bf16 MFMA
// - LDS: 4 buffers x (A 256x32 + B 256x32) bf16 = 128 KiB, XOR-swizzled
//   (swizzle: col_byte ^= ((row>>1)&3)<<4; applied on global SOURCE addr for the
//    linear global_load_lds write and on the ds_read addr — involution, rule 21)
// - prefetch 3 tiles ahead into buf[(t+3)&3] (last read at tile t-1 => race-free);
//   s_waitcnt vmcnt(8) at tile end guarantees tile t+1 landed; raw s_barrier
//   (no vmcnt(0) drain in main loop — T4)
// EPI: 0 = bf16 store (alpha applied); 2 = split@1152 + bias -> out0/out1 (fp32)
template<int EPI>
__global__ __launch_bounds__(512, 2)
void gemm256(const ushort* __restrict__ A, int lda,
             const ushort* __restrict__ Bm, int ldb,
             void* __restrict__ Cout, int ldc,
             int K, float alpha, int ntx, int row0,
             float* __restrict__ out0, float* __restrict__ out1,
             const float* __restrict__ bias0, const float* __restrict__ bias1)
{
  __shared__ __align__(16) ushort lds[65536];   // 128 KiB
  const int tid  = threadIdx.x;
  const int w    = tid >> 6, lane = tid & 63;
  const int wr   = w >> 2, wc = w & 3;

  // T1: bijective XCD swizzle (all grids divisible by 8)
  const int nwg = gridDim.x;
  const int wg  = blockIdx.x;
  const int swz = (wg & 7) * (nwg >> 3) + (wg >> 3);
  const int tx = swz % ntx, ty = swz / ntx;
  const int m0 = ty * 256, n0 = tx * 256;

  // ---- staging addresses (per-thread): seg s = w*2+i covers rows [s*16, s*16+16)
  // lane l writes LDS elems s*512 + l*8 => row s*16 + (l>>2), swz-col (l&3)*8.
  // inverse-swizzled global source col = 8*((l&3) ^ ((l>>3)&3))
  const int srow = lane >> 2;
  const int scol = 8 * ((lane & 3) ^ ((lane >> 3) & 3));
  const int sgA  = w * 2;
  const ushort* gA0 = A  + (size_t)(m0 + sgA * 16 + srow) * lda + scol;
  const ushort* gA1 = gA0 + (size_t)16 * lda;
  const ushort* gB0 = Bm + (size_t)(n0 + sgA * 16 + srow) * ldb + scol;
  const ushort* gB1 = gB0 + (size_t)16 * ldb;

  auto stage = [&](int t, int bf) {
    ushort* Lb = lds + bf * 16384;
    gload16(gA0 + t * 32, Lb + sgA * 512);
    gload16(gA1 + t * 32, Lb + sgA * 512 + 512);
    gload16(gB0 + t * 32, Lb + 8192 + sgA * 512);
    gload16(gB1 + t * 32, Lb + 8192 + sgA * 512 + 512);
  };

  // ---- ds_read fragment addresses (elems), col XOR-swizzled per row
  const int kq    = lane >> 4;                    // k-quarter (8 elems each)
  const int rowA0 = wr * 128 + (lane & 15);       // (row>>1)&3 invariant under +16*m
  const int adA   = rowA0 * 32 + 8 * (kq ^ ((rowA0 >> 1) & 3));
  const int rowB0 = wc * 64 + (lane & 15);
  const int adB   = rowB0 * 32 + 8 * (kq ^ ((rowB0 >> 1) & 3));

  f32x4 acc[8][4];
#pragma unroll
  for (int m = 0; m < 8; m++)
#pragma unroll
    for (int n = 0; n < 4; n++) acc[m][n] = f32x4{0.f, 0.f, 0.f, 0.f};

  const int nt = K >> 5;   // K-tiles of 32 (all K here are multiples of 32, nt >= 36)

  // prologue: 3 tiles in flight
  stage(0, 0); stage(1, 1); stage(2, 2);
  asm volatile("s_waitcnt vmcnt(8)" ::: "memory");   // tile 0 landed
  __builtin_amdgcn_s_barrier();

  for (int t = 0; t < nt; ++t) {
    const ushort* Lb = lds + (t & 3) * 16384;
    short8 a[8], b[4];
#pragma unroll
    for (int m = 0; m < 8; m++) a[m] = *(const short8*)(Lb + adA + m * 512);
#pragma unroll
    for (int n = 0; n < 4; n++) b[n] = *(const short8*)(Lb + 8192 + adB + n * 512);

    if (t + 3 < nt) stage(t + 3, (t + 3) & 3);

    __builtin_amdgcn_s_setprio(1);
#pragma unroll
    for (int m = 0; m < 8; m++)
#pragma unroll
      for (int n = 0; n < 4; n++)
        acc[m][n] = __builtin_amdgcn_mfma_f32_16x16x32_bf16(a[m], b[n], acc[m][n], 0, 0, 0);
    __builtin_amdgcn_s_setprio(0);

    // counted wait: ensure tile t+1 resident; keep deeper prefetches in flight
    if      (t + 3 < nt) asm volatile("s_waitcnt vmcnt(8)" ::: "memory");
    else if (t + 2 < nt) asm volatile("s_waitcnt vmcnt(4)" ::: "memory");
    else                 asm volatile("s_waitcnt vmcnt(0)" ::: "memory");
    __builtin_amdgcn_s_barrier();
  }

  // ---- epilogue: C frag mapping col=lane&15, row=(lane>>4)*4+v (m89-verified)
#pragma unroll
  for (int m = 0; m < 8; m++) {
#pragma unroll
    for (int v = 0; v < 4; v++) {
      const int row = m0 + wr * 128 + m * 16 + (lane >> 4) * 4 + v;
#pragma unroll
      for (int n = 0; n < 4; n++) {
        const int col = n0 + wc * 64 + n * 16 + (lane & 15);
        float val = acc[m][n][v] * alpha;
        if (EPI == 0) {
          ((ushort*)Cout)[(size_t)row * ldc + col] = f2bf(val);
        } else {
          const int orow = row0 + row;
          if (col < DD) out0[(size_t)orow * DD + col] = val + bias0[col];
          else          out1[(size_t)orow * DD + (col - DD)] = val + bias1[col - DD];
        }
      }
    }
  }
}

// ---------------- fp32 -> bf16 conversion ----------------
__global__ __launch_bounds__(256)
void cvt_f32_bf16(const float* __restrict__ src, ushort* __restrict__ dst, int n4)
{
  int stride = gridDim.x * blockDim.x;
  for (int i = blockIdx.x * blockDim.x + threadIdx.x; i < n4; i += stride) {
    float4 v = ((const float4*)src)[i];
    uint2 o;
    o.x = pack2(v.x, v.y);
    o.y = pack2(v.z, v.w);
    ((uint2*)dst)[i] = o;
  }
}

// ---------------- in-place RMS norm on Q/K segments of QKV rows ----------------
__global__ __launch_bounds__(256)
void rms_inplace(ushort* __restrict__ qkv,
                 const float* __restrict__ sq_text, const float* __restrict__ sq_pix,
                 const float* __restrict__ sk_text, const float* __restrict__ sk_pix)
{
  const int row = blockIdx.x;
  const int tid = threadIdx.x, wave = tid >> 6, lane = tid & 63;
  ushort* seg = qkv + (size_t)row * ROW + wave * 1152;
  const float* scale = (wave == 0) ? sq_text : (wave == 1) ? sq_pix
                     : (wave == 2) ? sk_text : sk_pix;
  float ss = 0.f;
  for (int g = lane; g < 144; g += 64) {
    uint4 p = *(const uint4*)(seg + g * 8);
    float f0 = bf2f(p.x), f1 = bf2f(p.x >> 16), f2 = bf2f(p.y), f3 = bf2f(p.y >> 16);
    float f4 = bf2f(p.z), f5 = bf2f(p.z >> 16), f6 = bf2f(p.w), f7 = bf2f(p.w >> 16);
    ss += f0*f0 + f1*f1 + f2*f2 + f3*f3 + f4*f4 + f5*f5 + f6*f6 + f7*f7;
  }
#pragma unroll
  for (int off = 32; off; off >>= 1) ss += __shfl_xor(ss, off);
  float rms = sqrtf(ss) * 0.0294627825f;  // 1/sqrt(1152)
  float inv = 1.0f / (rms + 1e-8f);
  for (int g = lane; g < 144; g += 64) {
    int d0 = g * 8;
    uint4 p = *(const uint4*)(seg + d0);
    float f[8];
    f[0]=bf2f(p.x); f[1]=bf2f(p.x>>16); f[2]=bf2f(p.y); f[3]=bf2f(p.y>>16);
    f[4]=bf2f(p.z); f[5]=bf2f(p.z>>16); f[6]=bf2f(p.w); f[7]=bf2f(p.w>>16);
    uint4 o;
    o.x = pack2(f[0]*scale[d0+0]*inv, f[1]*scale[d0+1]*inv);
    o.y = pack2(f[2]*scale[d0+2]*inv, f[3]*scale[d0+3]*inv);
    o.z = pack2(f[4]*scale[d0+4]*inv, f[5]*scale[d0+5]*inv);
    o.w = pack2(f[6]*scale[d0+6]*inv, f[7]*scale[d0+7]*inv);
    *(uint4*)(seg + d0) = o;
  }
}

// ---------------- V transpose: Vt[b][d][n] = V[b][n][d] ----------------
__global__ __launch_bounds__(256)
void transpose_v(const ushort* __restrict__ qkv, ushort* __restrict__ Vt)
{
  __shared__ ushort t[64][72];
  const int nb = blockIdx.x, db = blockIdx.y, b = blockIdx.z;
  const int tid = threadIdx.x;
  const int d0 = db * 64;
  const int srccol = 4608 + d0;
  const int rr = tid >> 3, cc = (tid & 7) * 8;
#pragma unroll
  for (int it = 0; it < 2; it++) {
    int r = rr + it * 32;
    uint4 p = *(const uint4*)(qkv + (size_t)(b * 4096 + nb * 64 + r) * ROW + srccol + cc);
    *(uint4*)&t[r][cc] = p;
  }
  __syncthreads();
#pragma unroll
  for (int it = 0; it < 2; it++) {
    int d = rr + it * 32;
    uint4 o;
    o.x = (uint32_t)t[cc+0][d] | ((uint32_t)t[cc+1][d] << 16);
    o.y = (uint32_t)t[cc+2][d] | ((uint32_t)t[cc+3][d] << 16);
    o.z = (uint32_t)t[cc+4][d] | ((uint32_t)t[cc+5][d] << 16);
    o.w = (uint32_t)t[cc+6][d] | ((uint32_t)t[cc+7][d] << 16);
    *(uint4*)(Vt + ((size_t)b * 2304 + d0 + d) * 4096 + nb * 64 + cc) = o;
  }
}

// ---------------- row softmax on bf16 S (4096 wide), in place ----------------
__global__ __launch_bounds__(256)
void softmax_bf16(ushort* __restrict__ S)
{
  const int row = blockIdx.x;
  ushort* sr = S + (size_t)row * 4096;
  const int tid = threadIdx.x, wave = tid >> 6, lane = tid & 63;
  __shared__ float red[8];
  uint4 p0 = ((const uint4*)sr)[tid * 2];
  uint4 p1 = ((const uint4*)sr)[tid * 2 + 1];
  float f[16];
  f[0]=bf2f(p0.x); f[1]=bf2f(p0.x>>16); f[2]=bf2f(p0.y); f[3]=bf2f(p0.y>>16);
  f[4]=bf2f(p0.z); f[5]=bf2f(p0.z>>16); f[6]=bf2f(p0.w); f[7]=bf2f(p0.w>>16);
  f[8]=bf2f(p1.x); f[9]=bf2f(p1.x>>16); f[10]=bf2f(p1.y); f[11]=bf2f(p1.y>>16);
  f[12]=bf2f(p1.z); f[13]=bf2f(p1.z>>16); f[14]=bf2f(p1.w); f[15]=bf2f(p1.w>>16);
  float mx = f[0];
#pragma unroll
  for (int j = 1; j < 16; j++) mx = fmaxf(mx, f[j]);
#pragma unroll
  for (int off = 32; off; off >>= 1) mx = fmaxf(mx, __shfl_xor(mx, off));
  if (lane == 0) red[wave] = mx;
  __syncthreads();
  mx = fmaxf(fmaxf(red[0], red[1]), fmaxf(red[2], red[3]));
  float s = 0.f;
#pragma unroll
  for (int j = 0; j < 16; j++) { f[j] = expf(f[j] - mx); s += f[j]; }
#pragma unroll
  for (int off = 32; off; off >>= 1) s += __shfl_xor(s, off);
  if (lane == 0) red[4 + wave] = s;
  __syncthreads();
  s = red[4] + red[5] + red[6] + red[7];
  float inv = 1.0f / s;
  uint4 o0, o1;
  o0.x = pack2(f[0]*inv, f[1]*inv);  o0.y = pack2(f[2]*inv, f[3]*inv);
  o0.z = pack2(f[4]*inv, f[5]*inv);  o0.w = pack2(f[6]*inv, f[7]*inv);
  o1.x = pack2(f[8]*inv, f[9]*inv);  o1.y = pack2(f[10]*inv, f[11]*inv);
  o1.z = pack2(f[12]*inv, f[13]*inv); o1.w = pack2(f[14]*inv, f[15]*inv);
  ((uint4*)sr)[tid * 2]     = o0;
  ((uint4*)sr)[tid * 2 + 1] = o1;
}

// ---------------- host launch ----------------
extern "C" void kernel_launch(void* const* d_in, const int* in_sizes, int n_in,
                              void* d_out, int out_size, void* d_ws, size_t ws_size,
                              hipStream_t stream)
{
  const float* x          = (const float*)d_in[0];
  const float* Wqkv_pix   = (const float*)d_in[2];
  const float* Wqkv_text  = (const float*)d_in[3];
  const float* sq_text    = (const float*)d_in[4];
  const float* sk_text    = (const float*)d_in[5];
  const float* sq_pix     = (const float*)d_in[6];
  const float* sk_pix     = (const float*)d_in[7];
  const float* Wproj_pix  = (const float*)d_in[8];
  const float* bproj_pix  = (const float*)d_in[9];
  const float* Wproj_text = (const float*)d_in[10];
  const float* bproj_text = (const float*)d_in[11];

  // workspace layout (bytes):
  //  QKV [0,          113,246,208)  8192x6912 bf16 [q_text q_pix k_text k_pix v_text v_pix]
  //      (Z 8192x2304 bf16 = 37.7 MB aliased at 0 — QKV fully dead after QK of each batch)
  //  Vt  [113,246,208,150,994,944)  2x 2304x4096 bf16   (xb aliased, dead before transpose)
  //  S   [150,994,944,184,549,376)  4096x4096 bf16      (Wb aliased, dead before first QK)
  //  Wpb [184,549,376,195,166,208)  2304x2304 bf16
  if (ws_size < 195166208ULL) return;
  char* ws = (char*)d_ws;
  ushort* QKV = (ushort*)(ws);
  ushort* Z   = (ushort*)(ws);
  ushort* Vt  = (ushort*)(ws + 113246208);
  ushort* S   = (ushort*)(ws + 150994944);
  ushort* Wpb = (ushort*)(ws + 184549376);
  ushort* xb  = (ushort*)(ws + 113246208);   // alias
  ushort* Wb  = (ushort*)(ws + 150994944);   // alias

  // conversions; Wb packed row-blocks: [q_text q_pix k_text k_pix v_text v_pix]
  cvt_f32_bf16<<<2048, 256, 0, stream>>>(x, xb, 9437184 / 4);
  for (int t = 0; t < 3; t++) {
    cvt_f32_bf16<<<512, 256, 0, stream>>>(Wqkv_text + (size_t)t * 1327104,
                                          Wb + (size_t)(2 * t) * 1327104, 1327104 / 4);
    cvt_f32_bf16<<<512, 256, 0, stream>>>(Wqkv_pix + (size_t)t * 1327104,
                                          Wb + (size_t)(2 * t + 1) * 1327104, 1327104 / 4);
  }
  cvt_f32_bf16<<<512, 256, 0, stream>>>(Wproj_pix, Wpb, 2654208 / 4);
  cvt_f32_bf16<<<512, 256, 0, stream>>>(Wproj_text, Wpb + 2654208, 2654208 / 4);

  // G1: QKV = xb @ Wb^T   (8192 x 6912, K=1152) — 864 WGs
  gemm256<0><<<dim3(864), 512, 0, stream>>>(xb, 1152, Wb, 1152, QKV, ROW,
                                            1152, 1.0f, 27, 0,
                                            nullptr, nullptr, nullptr, nullptr);
  rms_inplace<<<8192, 256, 0, stream>>>(QKV, sq_text, sq_pix, sk_text, sk_pix);
  {
    dim3 g(64, 36, 2);
    transpose_v<<<g, 256, 0, stream>>>(QKV, Vt);
  }

  const float scale = 1.0f / 48.0f;  // (2*1152)^-0.5
  const size_t slab = (size_t)4096 * ROW;
  for (int b = 0; b < 2; b++) {
    const ushort* Qb = QKV + b * slab;
    const ushort* Kb = QKV + b * slab + 2304;
    const ushort* Vb = Vt + (size_t)b * 2304 * 4096;
    ushort* Zb = Z + (size_t)b * 4096 * 2304;
    // S = scale * Qb @ Kb^T  (4096 x 4096, K=2304) — 256 WGs (exact CU fill)
    gemm256<0><<<dim3(256), 512, 0, stream>>>(Qb, ROW, Kb, ROW, S, 4096,
                                              2304, scale, 16, 0,
                                              nullptr, nullptr, nullptr, nullptr);
    softmax_bf16<<<4096, 256, 0, stream>>>(S);
    // Z = P @ V  (4096 x 2304, K=4096) — 144 WGs
    gemm256<0><<<dim3(144), 512, 0, stream>>>(S, 4096, Vb, 4096, Zb, 2304,
                                              4096, 1.0f, 9, 0,
                                              nullptr, nullptr, nullptr, nullptr);
  }

  // proj: out = Z @ Wp^T (8192 x 2304, K=2304), split at col 1152 + bias — 288 WGs
  {
    float* out0 = (float*)d_out;
    float* out1 = out0 + 9437184;
    gemm256<2><<<dim3(288), 512, 0, stream>>>(Z, 2304, Wpb, 2304, nullptr, 0,
                                              2304, 1.0f, 9, 0,
                                              out0, out1, bproj_pix, bproj_text);
  }
}

// Round 4
// 755.275 us; speedup vs baseline: 1.5614x; 1.0083x over previous
//
#include <hip/hip_runtime.h>
#include <hip/hip_bf16.h>
#include <stdint.h>

using short8 = __attribute__((ext_vector_type(8))) short;
using f32x4  = __attribute__((ext_vector_type(4))) float;

#define DD 1152
#define ROW 6912   // QKV row stride (elements)

static __device__ __forceinline__ float bf2f(uint32_t h){
  union { uint32_t u; float f; } v; v.u = (h & 0xffffu) << 16; return v.f;
}
static __device__ __forceinline__ ushort f2bf(float f){
  union { float f; uint32_t u; } v; v.f = f;
  uint32_t r = (v.u + 0x7fffu + ((v.u >> 16) & 1u)) >> 16;
  return (ushort)r;
}
static __device__ __forceinline__ uint32_t pack2(float a, float b){
  return (uint32_t)f2bf(a) | ((uint32_t)f2bf(b) << 16);
}

static __device__ __forceinline__ void gload16(const void* g, void* l){
  __builtin_amdgcn_global_load_lds(
      (const __attribute__((address_space(1))) void*)g,
      (__attribute__((address_space(3))) void*)l, 16, 0, 0);
}

// ================= 256x256 NT GEMM, BK=32, 8 waves, 4-deep LDS pipeline ==============
// C[m][n] = alpha * sum_k A[m][k]*B[n][k]
// - waves 2(M)x4(N), per-wave 128x64 output = 8x4 frags of 16x16x32 bf16 MFMA
// - LDS: 4 buffers x (A 256x32 + B 256x32) bf16 = 128 KiB, XOR-swizzled
//   (swizzle: col_byte ^= ((row>>1)&3)<<4; applied on global SOURCE addr for the
//    linear global_load_lds write and on the ds_read addr — involution, rule 21)
// - T3 phase split: each tile = 2 phases of 16 MFMA; per phase: {ds_read half
//   subtile + stage half of tile t+3 -> barrier -> setprio(1) MFMA setprio(0)}.
//   Regions between barriers carry MFMA(p) || ds_read(p+1) || gload — role-split
//   gives setprio something to arbitrate (T5), counted vmcnt (T4) spans barriers.
// - prefetch 3 tiles ahead into buf[(t+3)&3] (last read at tile t-1 => race-free);
//   vmcnt(8) at tile end guarantees tile t+1 landed; never vmcnt(0) mid-loop.
// EPI: 0 = bf16 store (alpha applied); 2 = split@1152 + bias -> out0/out1 (fp32)
template<int EPI>
__global__ __launch_bounds__(512, 2)
void gemm256(const ushort* __restrict__ A, int lda,
             const ushort* __restrict__ Bm, int ldb,
             void* __restrict__ Cout, int ldc,
             int K, float alpha, int ntx, int row0,
             float* __restrict__ out0, float* __restrict__ out1,
             const float* __restrict__ bias0, const float* __restrict__ bias1)
{
  __shared__ __align__(16) ushort lds[65536];   // 128 KiB
  const int tid  = threadIdx.x;
  const int w    = tid >> 6, lane = tid & 63;
  const int wr   = w >> 2, wc = w & 3;

  // T1: bijective XCD swizzle (all grids divisible by 8)
  const int nwg = gridDim.x;
  const int wg  = blockIdx.x;
  const int swz = (wg & 7) * (nwg >> 3) + (wg >> 3);
  const int tx = swz % ntx, ty = swz / ntx;
  const int m0 = ty * 256, n0 = tx * 256;

  // ---- staging addresses (per-thread): seg s = w*2+i covers rows [s*16, s*16+16)
  // lane l writes LDS elems s*512 + l*8 => row s*16 + (l>>2), swz-col (l&3)*8.
  // inverse-swizzled global source col = 8*((l&3) ^ ((l>>3)&3))
  const int srow = lane >> 2;
  const int scol = 8 * ((lane & 3) ^ ((lane >> 3) & 3));
  const int sgA  = w * 2;
  const ushort* gA0 = A  + (size_t)(m0 + sgA * 16 + srow) * lda + scol;
  const ushort* gA1 = gA0 + (size_t)16 * lda;
  const ushort* gB0 = Bm + (size_t)(n0 + sgA * 16 + srow) * ldb + scol;
  const ushort* gB1 = gB0 + (size_t)16 * ldb;

  auto stageAll = [&](int t, int bf) {
    ushort* Lb = lds + bf * 16384;
    gload16(gA0 + t * 32, Lb + sgA * 512);
    gload16(gA1 + t * 32, Lb + sgA * 512 + 512);
    gload16(gB0 + t * 32, Lb + 8192 + sgA * 512);
    gload16(gB1 + t * 32, Lb + 8192 + sgA * 512 + 512);
  };

  // ---- ds_read fragment addresses (elems), col XOR-swizzled per row
  const int kq    = lane >> 4;                    // k-quarter (8 elems each)
  const int rowA0 = wr * 128 + (lane & 15);       // (row>>1)&3 invariant under +16*m
  const int adA   = rowA0 * 32 + 8 * (kq ^ ((rowA0 >> 1) & 3));
  const int rowB0 = wc * 64 + (lane & 15);
  const int adB   = rowB0 * 32 + 8 * (kq ^ ((rowB0 >> 1) & 3));

  f32x4 acc[8][4];
#pragma unroll
  for (int m = 0; m < 8; m++)
#pragma unroll
    for (int n = 0; n < 4; n++) acc[m][n] = f32x4{0.f, 0.f, 0.f, 0.f};

  const int nt = K >> 5;   // K-tiles of 32 (all K here multiples of 32, nt >= 36)

  // prologue: 3 tiles in flight
  stageAll(0, 0); stageAll(1, 1); stageAll(2, 2);
  asm volatile("s_waitcnt vmcnt(8)" ::: "memory");   // tile 0 landed
  __builtin_amdgcn_s_barrier();

  for (int t = 0; t < nt; ++t) {
    const ushort* Lb = lds + (t & 3) * 16384;
    // ---- phase 1: read a[0..3] + b[0..3], stage A-halves of t+3
    short8 a0[4], b[4];
#pragma unroll
    for (int m = 0; m < 4; m++) a0[m] = *(const short8*)(Lb + adA + m * 512);
#pragma unroll
    for (int n = 0; n < 4; n++) b[n] = *(const short8*)(Lb + 8192 + adB + n * 512);
    if (t + 3 < nt) {
      ushort* Ld = lds + ((t + 3) & 3) * 16384;
      gload16(gA0 + (t + 3) * 32, Ld + sgA * 512);
      gload16(gA1 + (t + 3) * 32, Ld + sgA * 512 + 512);
    }
    __builtin_amdgcn_s_barrier();
    __builtin_amdgcn_s_setprio(1);
#pragma unroll
    for (int m = 0; m < 4; m++)
#pragma unroll
      for (int n = 0; n < 4; n++)
        acc[m][n] = __builtin_amdgcn_mfma_f32_16x16x32_bf16(a0[m], b[n], acc[m][n], 0, 0, 0);
    __builtin_amdgcn_s_setprio(0);

    // ---- phase 2: read a[4..7], stage B-halves of t+3, counted vmcnt
    short8 a1[4];
#pragma unroll
    for (int m = 0; m < 4; m++) a1[m] = *(const short8*)(Lb + adA + (m + 4) * 512);
    if (t + 3 < nt) {
      ushort* Ld = lds + ((t + 3) & 3) * 16384;
      gload16(gB0 + (t + 3) * 32, Ld + 8192 + sgA * 512);
      gload16(gB1 + (t + 3) * 32, Ld + 8192 + sgA * 512 + 512);
    }
    if      (t + 3 < nt) asm volatile("s_waitcnt vmcnt(8)" ::: "memory");
    else if (t + 2 < nt) asm volatile("s_waitcnt vmcnt(4)" ::: "memory");
    else                 asm volatile("s_waitcnt vmcnt(0)" ::: "memory");
    __builtin_amdgcn_s_barrier();
    __builtin_amdgcn_s_setprio(1);
#pragma unroll
    for (int m = 0; m < 4; m++)
#pragma unroll
      for (int n = 0; n < 4; n++)
        acc[m + 4][n] = __builtin_amdgcn_mfma_f32_16x16x32_bf16(a1[m], b[n], acc[m + 4][n], 0, 0, 0);
    __builtin_amdgcn_s_setprio(0);
  }

  // ---- epilogue: C frag mapping col=lane&15, row=(lane>>4)*4+v (m89-verified)
#pragma unroll
  for (int m = 0; m < 8; m++) {
#pragma unroll
    for (int v = 0; v < 4; v++) {
      const int row = m0 + wr * 128 + m * 16 + (lane >> 4) * 4 + v;
#pragma unroll
      for (int n = 0; n < 4; n++) {
        const int col = n0 + wc * 64 + n * 16 + (lane & 15);
        float val = acc[m][n][v] * alpha;
        if (EPI == 0) {
          ((ushort*)Cout)[(size_t)row * ldc + col] = f2bf(val);
        } else {
          const int orow = row0 + row;
          if (col < DD) out0[(size_t)orow * DD + col] = val + bias0[col];
          else          out1[(size_t)orow * DD + (col - DD)] = val + bias1[col - DD];
        }
      }
    }
  }
}

// ---------------- fp32 -> bf16 conversion ----------------
__global__ __launch_bounds__(256)
void cvt_f32_bf16(const float* __restrict__ src, ushort* __restrict__ dst, int n4)
{
  int stride = gridDim.x * blockDim.x;
  for (int i = blockIdx.x * blockDim.x + threadIdx.x; i < n4; i += stride) {
    float4 v = ((const float4*)src)[i];
    uint2 o;
    o.x = pack2(v.x, v.y);
    o.y = pack2(v.z, v.w);
    ((uint2*)dst)[i] = o;
  }
}

// ---------------- in-place RMS norm on Q/K segments of QKV rows ----------------
__global__ __launch_bounds__(256)
void rms_inplace(ushort* __restrict__ qkv,
                 const float* __restrict__ sq_text, const float* __restrict__ sq_pix,
                 const float* __restrict__ sk_text, const float* __restrict__ sk_pix)
{
  const int row = blockIdx.x;
  const int tid = threadIdx.x, wave = tid >> 6, lane = tid & 63;
  ushort* seg = qkv + (size_t)row * ROW + wave * 1152;
  const float* scale = (wave == 0) ? sq_text : (wave == 1) ? sq_pix
                     : (wave == 2) ? sk_text : sk_pix;
  float ss = 0.f;
  for (int g = lane; g < 144; g += 64) {
    uint4 p = *(const uint4*)(seg + g * 8);
    float f0 = bf2f(p.x), f1 = bf2f(p.x >> 16), f2 = bf2f(p.y), f3 = bf2f(p.y >> 16);
    float f4 = bf2f(p.z), f5 = bf2f(p.z >> 16), f6 = bf2f(p.w), f7 = bf2f(p.w >> 16);
    ss += f0*f0 + f1*f1 + f2*f2 + f3*f3 + f4*f4 + f5*f5 + f6*f6 + f7*f7;
  }
#pragma unroll
  for (int off = 32; off; off >>= 1) ss += __shfl_xor(ss, off);
  float rms = sqrtf(ss) * 0.0294627825f;  // 1/sqrt(1152)
  float inv = 1.0f / (rms + 1e-8f);
  for (int g = lane; g < 144; g += 64) {
    int d0 = g * 8;
    uint4 p = *(const uint4*)(seg + d0);
    float f[8];
    f[0]=bf2f(p.x); f[1]=bf2f(p.x>>16); f[2]=bf2f(p.y); f[3]=bf2f(p.y>>16);
    f[4]=bf2f(p.z); f[5]=bf2f(p.z>>16); f[6]=bf2f(p.w); f[7]=bf2f(p.w>>16);
    uint4 o;
    o.x = pack2(f[0]*scale[d0+0]*inv, f[1]*scale[d0+1]*inv);
    o.y = pack2(f[2]*scale[d0+2]*inv, f[3]*scale[d0+3]*inv);
    o.z = pack2(f[4]*scale[d0+4]*inv, f[5]*scale[d0+5]*inv);
    o.w = pack2(f[6]*scale[d0+6]*inv, f[7]*scale[d0+7]*inv);
    *(uint4*)(seg + d0) = o;
  }
}

// ---------------- V transpose: Vt[b][d][n] = V[b][n][d] ----------------
__global__ __launch_bounds__(256)
void transpose_v(const ushort* __restrict__ qkv, ushort* __restrict__ Vt)
{
  __shared__ ushort t[64][72];
  const int nb = blockIdx.x, db = blockIdx.y, b = blockIdx.z;
  const int tid = threadIdx.x;
  const int d0 = db * 64;
  const int srccol = 4608 + d0;
  const int rr = tid >> 3, cc = (tid & 7) * 8;
#pragma unroll
  for (int it = 0; it < 2; it++) {
    int r = rr + it * 32;
    uint4 p = *(const uint4*)(qkv + (size_t)(b * 4096 + nb * 64 + r) * ROW + srccol + cc);
    *(uint4*)&t[r][cc] = p;
  }
  __syncthreads();
#pragma unroll
  for (int it = 0; it < 2; it++) {
    int d = rr + it * 32;
    uint4 o;
    o.x = (uint32_t)t[cc+0][d] | ((uint32_t)t[cc+1][d] << 16);
    o.y = (uint32_t)t[cc+2][d] | ((uint32_t)t[cc+3][d] << 16);
    o.z = (uint32_t)t[cc+4][d] | ((uint32_t)t[cc+5][d] << 16);
    o.w = (uint32_t)t[cc+6][d] | ((uint32_t)t[cc+7][d] << 16);
    *(uint4*)(Vt + ((size_t)b * 2304 + d0 + d) * 4096 + nb * 64 + cc) = o;
  }
}

// ---------------- row softmax on bf16 S (4096 wide), in place ----------------
__global__ __launch_bounds__(256)
void softmax_bf16(ushort* __restrict__ S)
{
  const int row = blockIdx.x;
  ushort* sr = S + (size_t)row * 4096;
  const int tid = threadIdx.x, wave = tid >> 6, lane = tid & 63;
  __shared__ float red[8];
  uint4 p0 = ((const uint4*)sr)[tid * 2];
  uint4 p1 = ((const uint4*)sr)[tid * 2 + 1];
  float f[16];
  f[0]=bf2f(p0.x); f[1]=bf2f(p0.x>>16); f[2]=bf2f(p0.y); f[3]=bf2f(p0.y>>16);
  f[4]=bf2f(p0.z); f[5]=bf2f(p0.z>>16); f[6]=bf2f(p0.w); f[7]=bf2f(p0.w>>16);
  f[8]=bf2f(p1.x); f[9]=bf2f(p1.x>>16); f[10]=bf2f(p1.y); f[11]=bf2f(p1.y>>16);
  f[12]=bf2f(p1.z); f[13]=bf2f(p1.z>>16); f[14]=bf2f(p1.w); f[15]=bf2f(p1.w>>16);
  float mx = f[0];
#pragma unroll
  for (int j = 1; j < 16; j++) mx = fmaxf(mx, f[j]);
#pragma unroll
  for (int off = 32; off; off >>= 1) mx = fmaxf(mx, __shfl_xor(mx, off));
  if (lane == 0) red[wave] = mx;
  __syncthreads();
  mx = fmaxf(fmaxf(red[0], red[1]), fmaxf(red[2], red[3]));
  float s = 0.f;
#pragma unroll
  for (int j = 0; j < 16; j++) { f[j] = expf(f[j] - mx); s += f[j]; }
#pragma unroll
  for (int off = 32; off; off >>= 1) s += __shfl_xor(s, off);
  if (lane == 0) red[4 + wave] = s;
  __syncthreads();
  s = red[4] + red[5] + red[6] + red[7];
  float inv = 1.0f / s;
  uint4 o0, o1;
  o0.x = pack2(f[0]*inv, f[1]*inv);  o0.y = pack2(f[2]*inv, f[3]*inv);
  o0.z = pack2(f[4]*inv, f[5]*inv);  o0.w = pack2(f[6]*inv, f[7]*inv);
  o1.x = pack2(f[8]*inv, f[9]*inv);  o1.y = pack2(f[10]*inv, f[11]*inv);
  o1.z = pack2(f[12]*inv, f[13]*inv); o1.w = pack2(f[14]*inv, f[15]*inv);
  ((uint4*)sr)[tid * 2]     = o0;
  ((uint4*)sr)[tid * 2 + 1] = o1;
}

// ---------------- host launch ----------------
extern "C" void kernel_launch(void* const* d_in, const int* in_sizes, int n_in,
                              void* d_out, int out_size, void* d_ws, size_t ws_size,
                              hipStream_t stream)
{
  const float* x          = (const float*)d_in[0];
  const float* Wqkv_pix   = (const float*)d_in[2];
  const float* Wqkv_text  = (const float*)d_in[3];
  const float* sq_text    = (const float*)d_in[4];
  const float* sk_text    = (const float*)d_in[5];
  const float* sq_pix     = (const float*)d_in[6];
  const float* sk_pix     = (const float*)d_in[7];
  const float* Wproj_pix  = (const float*)d_in[8];
  const float* bproj_pix  = (const float*)d_in[9];
  const float* Wproj_text = (const float*)d_in[10];
  const float* bproj_text = (const float*)d_in[11];

  // workspace layout (bytes):
  //  QKV [0,          113,246,208)  8192x6912 bf16 [q_text q_pix k_text k_pix v_text v_pix]
  //      (Z 8192x2304 bf16 = 37.7 MB aliased at 0 — QKV fully dead after QK of each batch)
  //  Vt  [113,246,208,150,994,944)  2x 2304x4096 bf16   (xb aliased, dead before transpose)
  //  S   [150,994,944,184,549,376)  4096x4096 bf16      (Wb aliased, dead before first QK)
  //  Wpb [184,549,376,195,166,208)  2304x2304 bf16
  if (ws_size < 195166208ULL) return;
  char* ws = (char*)d_ws;
  ushort* QKV = (ushort*)(ws);
  ushort* Z   = (ushort*)(ws);
  ushort* Vt  = (ushort*)(ws + 113246208);
  ushort* S   = (ushort*)(ws + 150994944);
  ushort* Wpb = (ushort*)(ws + 184549376);
  ushort* xb  = (ushort*)(ws + 113246208);   // alias
  ushort* Wb  = (ushort*)(ws + 150994944);   // alias

  // conversions; Wb packed row-blocks: [q_text q_pix k_text k_pix v_text v_pix]
  cvt_f32_bf16<<<2048, 256, 0, stream>>>(x, xb, 9437184 / 4);
  for (int t = 0; t < 3; t++) {
    cvt_f32_bf16<<<512, 256, 0, stream>>>(Wqkv_text + (size_t)t * 1327104,
                                          Wb + (size_t)(2 * t) * 1327104, 1327104 / 4);
    cvt_f32_bf16<<<512, 256, 0, stream>>>(Wqkv_pix + (size_t)t * 1327104,
                                          Wb + (size_t)(2 * t + 1) * 1327104, 1327104 / 4);
  }
  cvt_f32_bf16<<<512, 256, 0, stream>>>(Wproj_pix, Wpb, 2654208 / 4);
  cvt_f32_bf16<<<512, 256, 0, stream>>>(Wproj_text, Wpb + 2654208, 2654208 / 4);

  // G1: QKV = xb @ Wb^T   (8192 x 6912, K=1152) — 864 WGs
  gemm256<0><<<dim3(864), 512, 0, stream>>>(xb, 1152, Wb, 1152, QKV, ROW,
                                            1152, 1.0f, 27, 0,
                                            nullptr, nullptr, nullptr, nullptr);
  rms_inplace<<<8192, 256, 0, stream>>>(QKV, sq_text, sq_pix, sk_text, sk_pix);
  {
    dim3 g(64, 36, 2);
    transpose_v<<<g, 256, 0, stream>>>(QKV, Vt);
  }

  const float scale = 1.0f / 48.0f;  // (2*1152)^-0.5
  const size_t slab = (size_t)4096 * ROW;
  for (int b = 0; b < 2; b++) {
    const ushort* Qb = QKV + b * slab;
    const ushort* Kb = QKV + b * slab + 2304;
    const ushort* Vb = Vt + (size_t)b * 2304 * 4096;
    ushort* Zb = Z + (size_t)b * 4096 * 2304;
    // S = scale * Qb @ Kb^T  (4096 x 4096, K=2304) — 256 WGs (exact CU fill)
    gemm256<0><<<dim3(256), 512, 0, stream>>>(Qb, ROW, Kb, ROW, S, 4096,
                                              2304, scale, 16, 0,
                                              nullptr, nullptr, nullptr, nullptr);
    softmax_bf16<<<4096, 256, 0, stream>>>(S);
    // Z = P @ V  (4096 x 2304, K=4096) — 144 WGs
    gemm256<0><<<dim3(144), 512, 0, stream>>>(S, 4096, Vb, 4096, Zb, 2304,
                                              4096, 1.0f, 9, 0,
                                              nullptr, nullptr, nullptr, nullptr);
  }

  // proj: out = Z @ Wp^T (8192 x 2304, K=2304), split at col 1152 + bias — 288 WGs
  {
    float* out0 = (float*)d_out;
    float* out1 = out0 + 9437184;
    gemm256<2><<<dim3(288), 512, 0, stream>>>(Z, 2304, Wpb, 2304, nullptr, 0,
                                              2304, 1.0f, 9, 0,
                                              out0, out1, bproj_pix, bproj_text);
  }
}